// Round 3
// baseline (119.805 us; speedup 1.0000x reference)
//
#include <hip/hip_runtime.h>
#include <hip/hip_cooperative_groups.h>

namespace cg = cooperative_groups;

// SpanIndexEncoder, single cooperative dispatch.
// out[t,f] = sum_n [s_n <= t <= e_n] embed[n,f]
//          = prefix over events: +embed[n] at t=s_n, -embed[n] at t=e_n+1 (valid spans).
//
// Block b owns tokens [8b, 8b+8):
//  A. scan starts/ends (8 KB, L2-broadcast) -> compact this chunk's ~12 events to LDS
//  B. register running-sum acc[0..7] over events (embed rows touched <=2x grid-wide)
//  C. csum[b] = acc[7]  (workspace written-before-read: NO memset, NO global atomics)
//     __threadfence + grid.sync
//  D. carry = sum csum[0..b): parity-split across 2 slices x 8 ILP chains.
//     ROUND-2 BUGFIX: tail is now a plain stride-2 loop. The old stride-4
//     remainder dropped csum[bp+2] whenever (b - bp) == 3 at tail entry
//     (~1/4 of slices) -> one missing chunk total = the absmax 10.75 failure.
//  E. out[8b+r] = carry + acc[r], coalesced 512 B rows

#define T_TOKENS 2048
#define N_NODES  1024
#define F        128
#define CHUNK    8
#define NCHUNK   (T_TOKENS / CHUNK)   // 256 blocks = 1/CU, trivially co-resident
#define NTHREADS 256

__global__ __launch_bounds__(NTHREADS)
void span_fused_kernel(const int* __restrict__ starts,
                       const int* __restrict__ ends,
                       const float* __restrict__ embed,
                       float* __restrict__ csum,     // d_ws: [NCHUNK][F], no init needed
                       float* __restrict__ out)
{
    __shared__ int   s_cnt;
    __shared__ int   s_ev[2 * N_NODES];   // worst case: every event in one chunk (8 KB)
    __shared__ float s_red[2][F];

    const int b     = blockIdx.x;
    const int t0    = b * CHUNK;
    const int tid   = threadIdx.x;
    const int slice = tid >> 7;           // 0..1
    const int f     = tid & (F - 1);      // 0..127

    if (tid == 0) s_cnt = 0;
    __syncthreads();

    // --- A: event detection, 4 nodes/thread via int4 (32 B/lane, coalesced) ---
    {
        const int4 s4 = ((const int4*)starts)[tid];
        const int4 e4 = ((const int4*)ends)[tid];
        const int  n0 = tid * 4;
        const int  ss[4] = {s4.x, s4.y, s4.z, s4.w};
        const int  ee[4] = {e4.x, e4.y, e4.z, e4.w};
        #pragma unroll
        for (int k = 0; k < 4; ++k) {
            const int s = ss[k], e = ee[k];
            if (s <= e) {                              // invalid spans: no events
                const int ps = s - t0;
                if ((unsigned)ps < CHUNK) {            // +embed[n] at row ps
                    const int idx = atomicAdd(&s_cnt, 1);
                    s_ev[idx] = (n0 + k) | (ps << 10);
                }
                const int pe = e + 1 - t0;
                if ((unsigned)pe < CHUNK) {            // -embed[n] at row pe (e+1==2048 excluded)
                    const int idx = atomicAdd(&s_cnt, 1);
                    s_ev[idx] = (n0 + k) | (pe << 10) | (1 << 13);
                }
            }
        }
    }
    __syncthreads();
    const int cnt = s_cnt;

    // --- B: intra-chunk running sums in registers (both slices duplicate; ~12 events) ---
    float acc[CHUNK];
    #pragma unroll
    for (int r = 0; r < CHUNK; ++r) acc[r] = 0.f;
    for (int i = 0; i < cnt; ++i) {
        const int   ent = s_ev[i];                    // LDS broadcast
        const int   n   = ent & (N_NODES - 1);
        const int   p   = (ent >> 10) & 7;
        const float w   = (ent & (1 << 13)) ? -1.f : 1.f;
        const float v   = w * embed[n * F + f];       // coalesced 256 B/wave, L2-resident
        #pragma unroll
        for (int r = 0; r < CHUNK; ++r)
            acc[r] += (r >= p) ? v : 0.f;             // branchless cndmask-add
    }

    // --- C: publish chunk total, grid-wide sync ---
    if (slice == 0) csum[b * F + f] = acc[CHUNK - 1];
    __threadfence();
    cg::this_grid().sync();

    // --- D: carry = sum of csum[0..b). Slice s takes chunks == s (mod 2), 8 chains. ---
    float c[8];
    #pragma unroll
    for (int j = 0; j < 8; ++j) c[j] = 0.f;
    int bp = slice;
    for (; bp + 16 <= b; bp += 16) {                  // 8 independent loads/iter/slice
        #pragma unroll
        for (int j = 0; j < 8; ++j)
            c[j] += csum[(bp + 2 * j) * F + f];
    }
    // Tail: plain stride-2 walk covers every remaining assigned chunk (<=8 loads).
    for (; bp < b; bp += 2)
        c[0] += csum[bp * F + f];
    const float part = ((c[0] + c[1]) + (c[2] + c[3])) + ((c[4] + c[5]) + (c[6] + c[7]));

    s_red[slice][f] = part;
    __syncthreads();
    const float carry = s_red[0][f] + s_red[1][f];

    // --- E: outputs. slice 0 -> rows 0..3, slice 1 -> rows 4..7; coalesced 512 B rows ---
    #pragma unroll
    for (int k = 0; k < 4; ++k) {
        const int r = slice * 4 + k;
        out[(t0 + r) * F + f] = carry + acc[r];
    }
}

extern "C" void kernel_launch(void* const* d_in, const int* in_sizes, int n_in,
                              void* d_out, int out_size, void* d_ws, size_t ws_size,
                              hipStream_t stream) {
    const int*   starts = (const int*)d_in[0];
    const int*   ends   = (const int*)d_in[1];
    const float* embed  = (const float*)d_in[2];
    float*       out    = (float*)d_out;
    float*       csum   = (float*)d_ws;   // 128 KB, written before read

    void* args[] = {(void*)&starts, (void*)&ends, (void*)&embed,
                    (void*)&csum, (void*)&out};
    hipLaunchCooperativeKernel((const void*)span_fused_kernel,
                               dim3(NCHUNK), dim3(NTHREADS), args, 0, stream);
}

// Round 4
// 68.060 us; speedup vs baseline: 1.7603x; 1.7603x over previous
//
#include <hip/hip_runtime.h>

// SpanIndexEncoder, two plain (graph-capturable) dispatches — no memset,
// no global atomics, no cooperative sync (round 3 showed grid.sync costs
// ~40 us here and defeats graph capture).
//
// out[t,f] = sum_n [s_n <= t <= e_n] embed[n,f]
//          = prefix over events: +embed[n] at t=s_n, -embed[n] at t=e_n+1.
//
// K1: block b owns tokens [8b,8b+8): detect its ~4 events from the 8 KB
//     starts/ends arrays, register running-sum acc[0..7], write
//     out rows = LOCAL prefix and csum[b] = chunk total (write-before-read:
//     poisoned workspace is harmless).
// K2: block b sums csum[0..b) via 2 slices x 16 ILP chains (32 outstanding
//     loads per f-lane -> ~8 latency rounds for the worst block), then
//     out[rows] += carry. Dispatch boundary provides cross-XCD visibility.

#define T_TOKENS 2048
#define N_NODES  1024
#define F        128
#define CHUNK    8
#define NCHUNK   (T_TOKENS / CHUNK)   // 256
#define NTHREADS 256

__global__ __launch_bounds__(NTHREADS)
void span_local_kernel(const int* __restrict__ starts,
                       const int* __restrict__ ends,
                       const float* __restrict__ embed,
                       float* __restrict__ csum,     // [NCHUNK][F], no init needed
                       float* __restrict__ out)
{
    __shared__ int s_cnt;
    __shared__ int s_ev[2 * N_NODES];   // worst case: all events in one chunk

    const int b     = blockIdx.x;
    const int t0    = b * CHUNK;
    const int tid   = threadIdx.x;
    const int slice = tid >> 7;          // 0..1
    const int f     = tid & (F - 1);     // 0..127

    if (tid == 0) s_cnt = 0;
    __syncthreads();

    // Event detection: 4 nodes/thread via int4 (32 B/lane, L2-broadcast).
    {
        const int4 s4 = ((const int4*)starts)[tid];
        const int4 e4 = ((const int4*)ends)[tid];
        const int  n0 = tid * 4;
        const int  ss[4] = {s4.x, s4.y, s4.z, s4.w};
        const int  ee[4] = {e4.x, e4.y, e4.z, e4.w};
        #pragma unroll
        for (int k = 0; k < 4; ++k) {
            const int s = ss[k], e = ee[k];
            if (s <= e) {                              // invalid spans: no events
                const int ps = s - t0;
                if ((unsigned)ps < CHUNK) {            // +embed[n] at row ps
                    const int idx = atomicAdd(&s_cnt, 1);
                    s_ev[idx] = (n0 + k) | (ps << 10);
                }
                const int pe = e + 1 - t0;
                if ((unsigned)pe < CHUNK) {            // -embed[n] at row pe
                    const int idx = atomicAdd(&s_cnt, 1);
                    s_ev[idx] = (n0 + k) | (pe << 10) | (1 << 13);
                }
            }
        }
    }
    __syncthreads();
    const int cnt = s_cnt;

    // Intra-chunk running sums in registers (~4 events avg; both slices
    // duplicate the cheap loop, each keeps all 8 rows).
    float acc[CHUNK];
    #pragma unroll
    for (int r = 0; r < CHUNK; ++r) acc[r] = 0.f;
    for (int i = 0; i < cnt; ++i) {
        const int   ent = s_ev[i];                    // LDS broadcast
        const int   n   = ent & (N_NODES - 1);
        const int   p   = (ent >> 10) & 7;
        const float w   = (ent & (1 << 13)) ? -1.f : 1.f;
        const float v   = w * embed[n * F + f];       // coalesced, L2/L3-resident
        #pragma unroll
        for (int r = 0; r < CHUNK; ++r)
            acc[r] += (r >= p) ? v : 0.f;             // branchless cndmask-add
    }

    // Local prefix out; slice 0 -> rows 0..3, slice 1 -> rows 4..7 + csum.
    #pragma unroll
    for (int k = 0; k < 4; ++k) {
        const int r = slice * 4 + k;
        out[(t0 + r) * F + f] = acc[r];
    }
    if (slice == 1) csum[b * F + f] = acc[CHUNK - 1];
}

__global__ __launch_bounds__(NTHREADS)
void span_carry_kernel(const float* __restrict__ csum,
                       float* __restrict__ out)
{
    __shared__ float s_red[2][F];

    const int b     = blockIdx.x;
    const int t0    = b * CHUNK;
    const int tid   = threadIdx.x;
    const int slice = tid >> 7;          // handles chunks == slice (mod 2)
    const int f     = tid & (F - 1);

    float c[16];
    #pragma unroll
    for (int j = 0; j < 16; ++j) c[j] = 0.f;

    int bp = slice;
    for (; bp + 32 <= b; bp += 32) {     // 16 independent loads in flight/lane
        #pragma unroll
        for (int j = 0; j < 16; ++j)
            c[j] += csum[(bp + 2 * j) * F + f];
    }
    for (; bp < b; bp += 2)              // stride-2 tail covers all assigned
        c[0] += csum[bp * F + f];

    float part = 0.f;
    #pragma unroll
    for (int j = 0; j < 16; ++j) part += c[j];

    s_red[slice][f] = part;
    __syncthreads();
    const float carry = s_red[0][f] + s_red[1][f];

    // out rows += carry; coalesced 512 B read-modify-write per row.
    #pragma unroll
    for (int k = 0; k < 4; ++k) {
        const int r = slice * 4 + k;
        out[(t0 + r) * F + f] += carry;
    }
}

extern "C" void kernel_launch(void* const* d_in, const int* in_sizes, int n_in,
                              void* d_out, int out_size, void* d_ws, size_t ws_size,
                              hipStream_t stream) {
    const int*   starts = (const int*)d_in[0];
    const int*   ends   = (const int*)d_in[1];
    const float* embed  = (const float*)d_in[2];
    float*       out    = (float*)d_out;
    float*       csum   = (float*)d_ws;   // 128 KB, written before read

    span_local_kernel<<<NCHUNK, NTHREADS, 0, stream>>>(starts, ends, embed, csum, out);
    span_carry_kernel<<<NCHUNK, NTHREADS, 0, stream>>>(csum, out);
}

// Round 5
// 61.171 us; speedup vs baseline: 1.9585x; 1.1126x over previous
//
#include <hip/hip_runtime.h>

// SpanIndexEncoder, ONE plain (graph-capturable) dispatch.
//
// Round-4 evidence: per-dispatch overhead in the captured graph is ~9 us
// (round1->round4: dropping one trivial memset dispatch saved 9 us), which
// dwarfs the ~5 us of actual compute. So the cross-block prefix (which
// forced K1+K2) is eliminated algebraically:
//
//   out[t0+r] = carry + local(r)
//   carry     = g(t0-1) = sum_{n: s_n <= t0-1 <= e_n} embed[n]   (pure
//               per-block reduction over ~170 covering rows -- no global
//               scan dependency; 8 slices x 4 ILP chains, L2-resident)
//   local(r)  = sum of signed events inside the chunk with pos <= r
//               (+embed[n] at s_n, -embed[n] at e_n+1; ~4 events/chunk)
//
// No workspace, no memset, no global atomics; covering-list compaction via
// wave ballot (one LDS atomic per wave, not per node). Each thread keeps
// ONLY its own output row's local accumulator (slice == row), so there is
// no runtime-indexed register array (scratch trap).

#define T_TOKENS 2048
#define N_NODES  1024
#define F        128
#define CHUNK    8
#define NCHUNK   (T_TOKENS / CHUNK)   // 256 blocks = 1/CU
#define NTHREADS 1024                 // 8 slices x 128 f-lanes
#define NSLICE   8

__global__ __launch_bounds__(NTHREADS)
void span_onepass_kernel(const int* __restrict__ starts,
                         const int* __restrict__ ends,
                         const float* __restrict__ embed,
                         float* __restrict__ out)
{
    __shared__ int   s_ncov;
    __shared__ int   s_nev;
    __shared__ int   s_cov[N_NODES];        // covering-node list (4 KB)
    __shared__ int   s_ev[2 * N_NODES];     // worst case: all events here (8 KB)
    __shared__ float s_red[NSLICE][F];      // carry partials (4 KB)

    const int b    = blockIdx.x;
    const int t0   = b * CHUNK;
    const int tid  = threadIdx.x;
    const int lane = tid & 63;

    if (tid == 0) { s_ncov = 0; s_nev = 0; }
    __syncthreads();

    // --- Detection: 1 node/thread. Covering test feeds the carry list via
    //     wave-ballot compaction; in-chunk events (rare, ~4) via LDS atomic.
    {
        const int  n     = tid;
        const int  s     = starts[n];
        const int  e     = ends[n];
        const bool valid = (s <= e);                       // invalid: no effect
        const bool cov   = valid & (b > 0) & (s <= t0 - 1) & (t0 - 1 <= e);

        const unsigned long long m = __ballot(cov);
        int base = 0;
        if (lane == 0) base = atomicAdd(&s_ncov, (int)__popcll(m));
        base = __shfl(base, 0);
        if (cov)
            s_cov[base + (int)__popcll(m & ((1ull << lane) - 1ull))] = n;

        if (valid) {
            const int ps = s - t0;
            if ((unsigned)ps < CHUNK) {                    // +embed[n] at row ps
                const int i = atomicAdd(&s_nev, 1);
                s_ev[i] = n | (ps << 10);
            }
            const int pe = e + 1 - t0;
            if ((unsigned)pe < CHUNK) {                    // -embed[n] at row pe
                const int i = atomicAdd(&s_nev, 1);
                s_ev[i] = n | (pe << 10) | (1 << 13);
            }
        }
    }
    __syncthreads();
    const int ncov = s_ncov;
    const int nev  = s_nev;

    const int slice = tid >> 7;          // 0..7 == output row r
    const int f     = tid & (F - 1);     // 0..127

    // --- Carry reduction: slice handles s_cov[slice::8], 4 ILP chains.
    //     LDS-read addresses are induction-based -> loads pipeline freely.
    float c0 = 0.f, c1 = 0.f, c2 = 0.f, c3 = 0.f;
    int i = slice;
    for (; i + 3 * NSLICE < ncov; i += 4 * NSLICE) {
        c0 += embed[s_cov[i             ] * F + f];
        c1 += embed[s_cov[i +     NSLICE] * F + f];
        c2 += embed[s_cov[i + 2 * NSLICE] * F + f];
        c3 += embed[s_cov[i + 3 * NSLICE] * F + f];
    }
    for (; i < ncov; i += NSLICE)        // tail stride == assignment stride
        c0 += embed[s_cov[i] * F + f];

    // --- Local signed prefix for THIS thread's row only (slice >= p test).
    float amine = 0.f;
    for (int j = 0; j < nev; ++j) {
        const int   ent = s_ev[j];                        // LDS broadcast
        const int   n   = ent & (N_NODES - 1);
        const int   p   = (ent >> 10) & 7;
        const float w   = (ent & (1 << 13)) ? -1.f : 1.f;
        const float v   = w * embed[n * F + f];           // coalesced, L2-hit
        amine += (slice >= p) ? v : 0.f;                  // branchless
    }

    // --- Combine slice partials and store one element per thread.
    s_red[slice][f] = (c0 + c1) + (c2 + c3);
    __syncthreads();
    float carry = 0.f;
    #pragma unroll
    for (int j = 0; j < NSLICE; ++j) carry += s_red[j][f];

    out[(t0 + slice) * F + f] = carry + amine;            // 2 waves = 512 B/row
}

extern "C" void kernel_launch(void* const* d_in, const int* in_sizes, int n_in,
                              void* d_out, int out_size, void* d_ws, size_t ws_size,
                              hipStream_t stream) {
    const int*   starts = (const int*)d_in[0];
    const int*   ends   = (const int*)d_in[1];
    const float* embed  = (const float*)d_in[2];
    float*       out    = (float*)d_out;

    span_onepass_kernel<<<NCHUNK, NTHREADS, 0, stream>>>(starts, ends, embed, out);
}